// Round 5
// baseline (236.509 us; speedup 1.0000x reference)
//
#include <hip/hip_runtime.h>
#include <hip/hip_bf16.h>

#define DD 1024
#define BM 128
#define BN 128
#define BK 64
#define TAU 32.0f
#define PTH 0.1f
#define BIGF 3.0e38f

typedef __attribute__((ext_vector_type(8))) short bf16x8;
typedef __attribute__((ext_vector_type(4))) float f32x4;

__device__ __forceinline__ unsigned short f2bf(float f) {
  unsigned u = __float_as_uint(f);
  u = (u + 0x7FFFu + ((u >> 16) & 1u)) >> 16;
  return (unsigned short)u;
}

// sorted-ascending top-5-smallest insert via med3: 5 independent VALU ops
__device__ __forceinline__ void insert5(float (&t)[5], float v) {
  float t0 = t[0], t1 = t[1], t2 = t[2], t3 = t[3], t4 = t[4];
  t[0] = fminf(t0, v);
  t[1] = __builtin_amdgcn_fmed3f(v, t0, t1);
  t[2] = __builtin_amdgcn_fmed3f(v, t1, t2);
  t[3] = __builtin_amdgcn_fmed3f(v, t2, t3);
  t[4] = __builtin_amdgcn_fmed3f(v, t3, t4);
}

__device__ __forceinline__ void gload16(const unsigned short* g, unsigned short* l) {
  __builtin_amdgcn_global_load_lds(
      (const __attribute__((address_space(1))) void*)g,
      (__attribute__((address_space(3))) void*)l, 16, 0, 0);
}

// one wave per row: squared norm (f32) + bf16 cast of X
__global__ void prep_kernel(const float* __restrict__ x, unsigned short* __restrict__ xbf,
                            float* __restrict__ sq) {
  const int row  = blockIdx.x * 4 + (threadIdx.x >> 6);
  const int lane = threadIdx.x & 63;
  const float4* xr = reinterpret_cast<const float4*>(x) + (size_t)row * (DD / 4);
  float s = 0.f;
  #pragma unroll
  for (int i = 0; i < 4; ++i) {
    float4 v = xr[lane + 64 * i];
    s += v.x * v.x + v.y * v.y + v.z * v.z + v.w * v.w;
    ushort4 b;
    b.x = f2bf(v.x); b.y = f2bf(v.y); b.z = f2bf(v.z); b.w = f2bf(v.w);
    *reinterpret_cast<ushort4*>(xbf + (size_t)row * DD + (size_t)(lane + 64 * i) * 4) = b;
  }
  #pragma unroll
  for (int off = 32; off > 0; off >>= 1) s += __shfl_xor(s, off, 64);
  if (lane == 0) sq[row] = s;
}

// Symmetric flash top-k: one block per upper-triangle 128x128 block-pair (I,J).
// d^2 tile folds into rows of I (row-side) AND rows of J (col-side, d symmetric);
// diagonal blocks skip col-side (would duplicate pairs). Each row r gets exactly
// one top-5 contribution per column-block J -> partial[r][J][5].
__global__ __launch_bounds__(256, 2)
void gemm_topk_kernel(const unsigned short* __restrict__ xbf, const float* __restrict__ sq,
                      float* __restrict__ partial, int N) {
  __shared__ union ShMem {
    struct { unsigned short A[BM * BK]; unsigned short B[BN * BK]; } t;  // 32 KB, swizzled
    float mrg[64][32][5];   // row-merge scratch (40 KB)
    float mrgc[128][8][5];  // col-merge scratch (20 KB)
  } sh;
  static_assert(sizeof(ShMem) <= 65536, "LDS over 64KB");

  const int tid  = threadIdx.x;
  const int lane = tid & 63;
  const int wid  = tid >> 6;
  const int wr   = wid >> 1;   // 0..1 -> 64-row half
  const int wc   = wid & 1;    // 0..1 -> 64-col half
  const int l15  = lane & 15;
  const int l4   = lane >> 4;  // 0..3

  const int NBv = N / BM;  // 64
  // decode upper-triangle pair: start(I) = I*NBv - I*(I-1)/2
  int bid = blockIdx.x;
  int I = (int)(((2.f * NBv + 1.f) -
                 sqrtf((2.f * NBv + 1.f) * (2.f * NBv + 1.f) - 8.f * (float)bid)) * 0.5f);
  I = max(0, min(NBv - 1, I));
  #define TSTART(i) ((i) * NBv - ((i) * ((i) - 1)) / 2)
  while (I + 1 <= NBv - 1 && TSTART(I + 1) <= bid) ++I;
  while (TSTART(I) > bid) --I;
  const int J = I + (bid - TSTART(I));
  #undef TSTART

  const int row0 = I * BM;
  const int cb   = J * BM;
  const bool diag = (I == J);

  // staging source: inst j covers LDS slots j*64+lane; row = j*8 + (lane>>3),
  // phys slot (lane&7) -> logical col-slot = (lane&7) ^ (row&7), row&7 == lane>>3
  const int lr = lane >> 3;
  const int lc = (lane & 7) ^ lr;
  const size_t offl = (size_t)lr * DD + lc * 8;  // k-invariant per-lane elem offset
  const int jbase = wid * 4;
  unsigned short* ldsA = sh.t.A;
  unsigned short* ldsB = sh.t.B;

  // fragment read swizzle: row&7 == l15&7 for every fragment row
  const int xs0 = ((l4) ^ (l15 & 7)) * 8;        // ks=0 elem offset within row
  const int xs1 = ((4 + l4) ^ (l15 & 7)) * 8;    // ks=1

  f32x4 acc[4][4];
  #pragma unroll
  for (int mi = 0; mi < 4; ++mi)
    #pragma unroll
    for (int ni = 0; ni < 4; ++ni) {
      f32x4 z; z[0] = 0.f; z[1] = 0.f; z[2] = 0.f; z[3] = 0.f;
      acc[mi][ni] = z;
    }

  for (int k0 = 0; k0 < DD; k0 += BK) {
    __syncthreads();  // prior LDS reads done
    #pragma unroll
    for (int jj = 0; jj < 4; ++jj) {
      const int j = jbase + jj;
      gload16(xbf + (size_t)(row0 + j * 8) * DD + k0 + offl, ldsA + j * 512);
      gload16(xbf + (size_t)(cb   + j * 8) * DD + k0 + offl, ldsB + j * 512);
    }
    __syncthreads();  // vmcnt(0) drained before barrier -> tiles landed

    #pragma unroll
    for (int ks = 0; ks < 2; ++ks) {
      const int xs = ks ? xs1 : xs0;
      bf16x8 af[4], bfr[4];
      #pragma unroll
      for (int mi = 0; mi < 4; ++mi)
        af[mi] = *reinterpret_cast<const bf16x8*>(ldsA + (wr * 64 + mi * 16 + l15) * BK + xs);
      #pragma unroll
      for (int ni = 0; ni < 4; ++ni)
        bfr[ni] = *reinterpret_cast<const bf16x8*>(ldsB + (wc * 64 + ni * 16 + l15) * BK + xs);
      #pragma unroll
      for (int mi = 0; mi < 4; ++mi)
        #pragma unroll
        for (int ni = 0; ni < 4; ++ni)
          acc[mi][ni] = __builtin_amdgcn_mfma_f32_16x16x32_bf16(af[mi], bfr[ni], acc[mi][ni], 0, 0, 0);
    }
  }

  // d^2 = sq_r + sq_c - 2*dot; fold row-side (t5r) and, off-diag, col-side (t5c)
  float t5r[16][5], t5c[4][5];
  #pragma unroll
  for (int i = 0; i < 16; ++i)
    #pragma unroll
    for (int j = 0; j < 5; ++j) t5r[i][j] = BIGF;
  #pragma unroll
  for (int i = 0; i < 4; ++i)
    #pragma unroll
    for (int j = 0; j < 5; ++j) t5c[i][j] = BIGF;

  float sqr_[16];
  #pragma unroll
  for (int mi = 0; mi < 4; ++mi)
    #pragma unroll
    for (int r = 0; r < 4; ++r)
      sqr_[mi * 4 + r] = sq[row0 + wr * 64 + mi * 16 + l4 * 4 + r];

  #pragma unroll
  for (int ni = 0; ni < 4; ++ni) {
    const int gc = cb + wc * 64 + ni * 16 + l15;
    const float sqc = sq[gc];
    #pragma unroll
    for (int mi = 0; mi < 4; ++mi) {
      #pragma unroll
      for (int r = 0; r < 4; ++r) {
        float v = sqr_[mi * 4 + r] + sqc - 2.0f * acc[mi][ni][r];
        if (diag) {
          const int gr = row0 + wr * 64 + mi * 16 + l4 * 4 + r;
          v = (gc == gr) ? BIGF : v;  // exclude self
        }
        insert5(t5r[mi * 4 + r], v);
        if (!diag) insert5(t5c[ni], v);
      }
    }
  }

  // row-side merge in two passes (64 rows each; 32 contributors per row) -> slot J
  #pragma unroll
  for (int pass = 0; pass < 2; ++pass) {
    __syncthreads();
    if (wr == pass) {
      #pragma unroll
      for (int mi = 0; mi < 4; ++mi)
        #pragma unroll
        for (int r = 0; r < 4; ++r)
          #pragma unroll
          for (int j = 0; j < 5; ++j)
            sh.mrg[mi * 16 + l4 * 4 + r][wc * 16 + l15][j] = t5r[mi * 4 + r][j];
    }
    __syncthreads();
    if (tid < 64) {
      float m[5] = {BIGF, BIGF, BIGF, BIGF, BIGF};
      for (int s2 = 0; s2 < 32; ++s2)
        #pragma unroll
        for (int j = 0; j < 5; ++j)
          insert5(m, sh.mrg[tid][s2][j]);
      float* p = partial + ((size_t)(row0 + pass * 64 + tid) * NBv + J) * 5;
      #pragma unroll
      for (int j = 0; j < 5; ++j) p[j] = m[j];
    }
  }

  // col-side merge (128 cols; 8 contributors per col) -> rows of block J, slot I
  if (!diag) {
    __syncthreads();
    #pragma unroll
    for (int ni = 0; ni < 4; ++ni)
      #pragma unroll
      for (int j = 0; j < 5; ++j)
        sh.mrgc[wc * 64 + ni * 16 + l15][wr * 4 + l4][j] = t5c[ni][j];
    __syncthreads();
    if (tid < 128) {
      float m[5] = {BIGF, BIGF, BIGF, BIGF, BIGF};
      #pragma unroll
      for (int s2 = 0; s2 < 8; ++s2)
        #pragma unroll
        for (int j = 0; j < 5; ++j)
          insert5(m, sh.mrgc[tid][s2][j]);
      float* p = partial + ((size_t)(cb + tid) * NBv + I) * 5;
      #pragma unroll
      for (int j = 0; j < 5; ++j) p[j] = m[j];
    }
  }
}

__global__ void weight_kernel(const float* __restrict__ partial, float* __restrict__ w, int N) {
  const int r = blockIdx.x * 256 + threadIdx.x;
  if (r >= N) return;
  const int NBv = N / BM;
  float m[5] = {BIGF, BIGF, BIGF, BIGF, BIGF};
  const float* p = partial + (size_t)r * NBv * 5;
  for (int s = 0; s < NBv * 5; ++s) insert5(m, p[s]);
  float sc = 0.f;
  #pragma unroll
  for (int j = 0; j < 5; ++j) sc += sqrtf(fmaxf(m[j], 0.f));
  sc *= 0.2f;  // mean of 5
  w[r] = (sc > PTH) ? expf(-sc / TAU) : 0.f;
}

__global__ void apply_kernel(const float* __restrict__ xr, const float* __restrict__ xi,
                             const float* __restrict__ w, float* __restrict__ out, int N) {
  const size_t i = (size_t)blockIdx.x * blockDim.x + threadIdx.x;
  const size_t tot = (size_t)N * (DD / 4);
  if (i >= tot) return;
  const int row = (int)(i >> 8);  // DD/4 = 256 float4 per row
  const float wt = w[row];
  float4 a = reinterpret_cast<const float4*>(xr)[i];
  a.x *= wt; a.y *= wt; a.z *= wt; a.w *= wt;
  reinterpret_cast<float4*>(out)[i] = a;
  float4 b = reinterpret_cast<const float4*>(xi)[i];
  b.x *= wt; b.y *= wt; b.z *= wt; b.w *= wt;
  reinterpret_cast<float4*>(out)[tot + i] = b;
}

extern "C" void kernel_launch(void* const* d_in, const int* in_sizes, int n_in,
                              void* d_out, int out_size, void* d_ws, size_t ws_size,
                              hipStream_t stream) {
  const float* xr = (const float*)d_in[0];
  const float* xi = (const float*)d_in[1];
  float* out = (float*)d_out;
  const int N = in_sizes[0] / DD;  // 8192
  const int NBv = N / BM;          // 64

  unsigned short* xbf = (unsigned short*)d_ws;                       // N*DD bf16
  float* sq      = (float*)((char*)d_ws + (size_t)N * DD * 2);       // N f32
  float* partial = sq + N;                                           // N*NBv*5 f32 (10.5 MB)
  float* w       = partial + (size_t)N * NBv * 5;                    // N f32

  prep_kernel<<<N / 4, 256, 0, stream>>>(xr, xbf, sq);
  const int npairs = NBv * (NBv + 1) / 2;  // 2080
  gemm_topk_kernel<<<npairs, 256, 0, stream>>>(xbf, sq, partial, N);
  weight_kernel<<<(N + 255) / 256, 256, 0, stream>>>(partial, w, N);
  apply_kernel<<<N, 256, 0, stream>>>(xr, xi, w, out, N);
}

// Round 6
// 141.927 us; speedup vs baseline: 1.6664x; 1.6664x over previous
//
#include <hip/hip_runtime.h>
#include <hip/hip_bf16.h>

#define DD 1024
#define BM 128
#define BN 128
#define BK 64
#define TAU 32.0f
#define PTH 0.1f
#define BIGF 3.0e38f

typedef __attribute__((ext_vector_type(8))) short bf16x8;
typedef __attribute__((ext_vector_type(4))) float f32x4;

__device__ __forceinline__ unsigned short f2bf(float f) {
  unsigned u = __float_as_uint(f);
  u = (u + 0x7FFFu + ((u >> 16) & 1u)) >> 16;
  return (unsigned short)u;
}

// sorted-ascending top-5-smallest insert via med3: 5 independent VALU ops
__device__ __forceinline__ void insert5(float (&t)[5], float v) {
  float t0 = t[0], t1 = t[1], t2 = t[2], t3 = t[3], t4 = t[4];
  t[0] = fminf(t0, v);
  t[1] = __builtin_amdgcn_fmed3f(v, t0, t1);
  t[2] = __builtin_amdgcn_fmed3f(v, t1, t2);
  t[3] = __builtin_amdgcn_fmed3f(v, t2, t3);
  t[4] = __builtin_amdgcn_fmed3f(v, t3, t4);
}

__device__ __forceinline__ void gload16(const unsigned short* g, unsigned short* l) {
  __builtin_amdgcn_global_load_lds(
      (const __attribute__((address_space(1))) void*)g,
      (__attribute__((address_space(3))) void*)l, 16, 0, 0);
}

// one wave per row: squared norm (f32) + bf16 cast of X
__global__ void prep_kernel(const float* __restrict__ x, unsigned short* __restrict__ xbf,
                            float* __restrict__ sq) {
  const int row  = blockIdx.x * 4 + (threadIdx.x >> 6);
  const int lane = threadIdx.x & 63;
  const float4* xr = reinterpret_cast<const float4*>(x) + (size_t)row * (DD / 4);
  float s = 0.f;
  #pragma unroll
  for (int i = 0; i < 4; ++i) {
    float4 v = xr[lane + 64 * i];
    s += v.x * v.x + v.y * v.y + v.z * v.z + v.w * v.w;
    ushort4 b;
    b.x = f2bf(v.x); b.y = f2bf(v.y); b.z = f2bf(v.z); b.w = f2bf(v.w);
    *reinterpret_cast<ushort4*>(xbf + (size_t)row * DD + (size_t)(lane + 64 * i) * 4) = b;
  }
  #pragma unroll
  for (int off = 32; off > 0; off >>= 1) s += __shfl_xor(s, off, 64);
  if (lane == 0) sq[row] = s;
}

// Symmetric flash top-k over upper-triangle 128x128 block-pairs (I,J), ordered in
// 8x8 super-tiles (4MB working set = one XCD L2) with bijective chunked XCD swizzle.
// Merge scratch padded to odd strides (161/41 floats) -> bank-conflict-free.
__global__ __launch_bounds__(256, 3)
void gemm_topk_kernel(const unsigned short* __restrict__ xbf, const float* __restrict__ sq,
                      float* __restrict__ partial, int N) {
  __shared__ union ShMem {
    struct { unsigned short A[BM * BK]; unsigned short B[BN * BK]; } t;  // 32 KB, swizzled
    float mrg[64 * 161];   // row-merge: row*161 + contrib*5 + j  (41.2 KB)
    float mrgc[128 * 41];  // col-merge: col*41 + contrib*5 + j   (21 KB)
  } sh;
  static_assert(sizeof(ShMem) <= 65536, "LDS over 64KB");

  const int tid  = threadIdx.x;
  const int lane = tid & 63;
  const int wid  = tid >> 6;
  const int wr   = wid >> 1;   // 0..1 -> 64-row half
  const int wc   = wid & 1;    // 0..1 -> 64-col half
  const int l15  = lane & 15;
  const int l4   = lane >> 4;  // 0..3

  const int NBv = N / BM;      // 64 block-rows
  const int NSB = NBv / 8;     // 8 super-rows

  // bijective chunked XCD swizzle (gridDim.x divisible by 8)
  const int chunk = gridDim.x >> 3;
  const int swz = (blockIdx.x & 7) * chunk + (blockIdx.x >> 3);
  const int sp  = swz >> 6;    // super-pair (triangle over NSB)
  const int sub = swz & 63;

  int SI = 0;
  #define TSTART(i) ((i) * NSB - ((i) * ((i) - 1)) / 2)
  while (SI + 1 < NSB && TSTART(SI + 1) <= sp) ++SI;
  const int SJ = SI + (sp - TSTART(SI));
  #undef TSTART
  const int si = sub >> 3, sj = sub & 7;
  if (SI == SJ && si > sj) return;  // lower-triangle sub-pair of diagonal super-pair
  const int I = SI * 8 + si, J = SJ * 8 + sj;

  const int row0 = I * BM;
  const int cb   = J * BM;
  const bool diag = (I == J);

  // staging source: inst j covers LDS slots j*64+lane; row = j*8 + (lane>>3),
  // phys slot (lane&7) -> logical col-slot = (lane&7) ^ (row&7), row&7 == lane>>3
  const int lr = lane >> 3;
  const int lc = (lane & 7) ^ lr;
  const size_t offl = (size_t)lr * DD + lc * 8;  // k-invariant per-lane elem offset
  const int jbase = wid * 4;
  unsigned short* ldsA = sh.t.A;
  unsigned short* ldsB = sh.t.B;

  // fragment read swizzle: row&7 == l15&7 for every fragment row
  const int xs0 = ((l4) ^ (l15 & 7)) * 8;        // ks=0 elem offset within row
  const int xs1 = ((4 + l4) ^ (l15 & 7)) * 8;    // ks=1

  f32x4 acc[4][4];
  #pragma unroll
  for (int mi = 0; mi < 4; ++mi)
    #pragma unroll
    for (int ni = 0; ni < 4; ++ni) {
      f32x4 z; z[0] = 0.f; z[1] = 0.f; z[2] = 0.f; z[3] = 0.f;
      acc[mi][ni] = z;
    }

  for (int k0 = 0; k0 < DD; k0 += BK) {
    __syncthreads();  // prior LDS reads done
    #pragma unroll
    for (int jj = 0; jj < 4; ++jj) {
      const int j = jbase + jj;
      gload16(xbf + (size_t)(row0 + j * 8) * DD + k0 + offl, ldsA + j * 512);
      gload16(xbf + (size_t)(cb   + j * 8) * DD + k0 + offl, ldsB + j * 512);
    }
    __syncthreads();  // vmcnt(0) drained before barrier -> tiles landed

    #pragma unroll
    for (int ks = 0; ks < 2; ++ks) {
      const int xs = ks ? xs1 : xs0;
      bf16x8 af[4], bfr[4];
      #pragma unroll
      for (int mi = 0; mi < 4; ++mi)
        af[mi] = *reinterpret_cast<const bf16x8*>(ldsA + (wr * 64 + mi * 16 + l15) * BK + xs);
      #pragma unroll
      for (int ni = 0; ni < 4; ++ni)
        bfr[ni] = *reinterpret_cast<const bf16x8*>(ldsB + (wc * 64 + ni * 16 + l15) * BK + xs);
      #pragma unroll
      for (int mi = 0; mi < 4; ++mi)
        #pragma unroll
        for (int ni = 0; ni < 4; ++ni)
          acc[mi][ni] = __builtin_amdgcn_mfma_f32_16x16x32_bf16(af[mi], bfr[ni], acc[mi][ni], 0, 0, 0);
    }
  }

  // d^2 = sq_r + sq_c - 2*dot; fold row-side (t5r) and, off-diag, col-side (t5c)
  float t5r[16][5], t5c[4][5];
  #pragma unroll
  for (int i = 0; i < 16; ++i)
    #pragma unroll
    for (int j = 0; j < 5; ++j) t5r[i][j] = BIGF;
  #pragma unroll
  for (int i = 0; i < 4; ++i)
    #pragma unroll
    for (int j = 0; j < 5; ++j) t5c[i][j] = BIGF;

  float sqr_[16];
  #pragma unroll
  for (int mi = 0; mi < 4; ++mi)
    #pragma unroll
    for (int r = 0; r < 4; ++r)
      sqr_[mi * 4 + r] = sq[row0 + wr * 64 + mi * 16 + l4 * 4 + r];

  #pragma unroll
  for (int ni = 0; ni < 4; ++ni) {
    const int gc = cb + wc * 64 + ni * 16 + l15;
    const float sqc = sq[gc];
    #pragma unroll
    for (int mi = 0; mi < 4; ++mi) {
      #pragma unroll
      for (int r = 0; r < 4; ++r) {
        float v = sqr_[mi * 4 + r] + sqc - 2.0f * acc[mi][ni][r];
        if (diag) {
          const int gr = row0 + wr * 64 + mi * 16 + l4 * 4 + r;
          v = (gc == gr) ? BIGF : v;  // exclude self
        }
        insert5(t5r[mi * 4 + r], v);
        if (!diag) insert5(t5c[ni], v);
      }
    }
  }

  // row-side merge in two passes (64 rows each; 32 contributors per row) -> slot J
  #pragma unroll
  for (int pass = 0; pass < 2; ++pass) {
    __syncthreads();
    if (wr == pass) {
      #pragma unroll
      for (int mi = 0; mi < 4; ++mi)
        #pragma unroll
        for (int r = 0; r < 4; ++r)
          #pragma unroll
          for (int j = 0; j < 5; ++j)
            sh.mrg[(mi * 16 + l4 * 4 + r) * 161 + (wc * 16 + l15) * 5 + j] = t5r[mi * 4 + r][j];
    }
    __syncthreads();
    if (tid < 64) {
      float m[5] = {BIGF, BIGF, BIGF, BIGF, BIGF};
      for (int s2 = 0; s2 < 32; ++s2)
        #pragma unroll
        for (int j = 0; j < 5; ++j)
          insert5(m, sh.mrg[tid * 161 + s2 * 5 + j]);
      float* p = partial + ((size_t)(row0 + pass * 64 + tid) * NBv + J) * 5;
      #pragma unroll
      for (int j = 0; j < 5; ++j) p[j] = m[j];
    }
  }

  // col-side merge (128 cols; 8 contributors per col) -> rows of block J, slot I
  if (!diag) {
    __syncthreads();
    #pragma unroll
    for (int ni = 0; ni < 4; ++ni)
      #pragma unroll
      for (int j = 0; j < 5; ++j)
        sh.mrgc[(wc * 64 + ni * 16 + l15) * 41 + (wr * 4 + l4) * 5 + j] = t5c[ni][j];
    __syncthreads();
    if (tid < 128) {
      float m[5] = {BIGF, BIGF, BIGF, BIGF, BIGF};
      #pragma unroll
      for (int s2 = 0; s2 < 8; ++s2)
        #pragma unroll
        for (int j = 0; j < 5; ++j)
          insert5(m, sh.mrgc[tid * 41 + s2 * 5 + j]);
      float* p = partial + ((size_t)(cb + tid) * NBv + I) * 5;
      #pragma unroll
      for (int j = 0; j < 5; ++j) p[j] = m[j];
    }
  }
}

// one wave per row: parallel load of 64 slot-top5s + butterfly shuffle merge
__global__ void weight_kernel(const float* __restrict__ partial, float* __restrict__ w, int N) {
  const int r    = blockIdx.x * 4 + (threadIdx.x >> 6);
  const int lane = threadIdx.x & 63;
  const float* p = partial + ((size_t)r * 64 + lane) * 5;
  float t[5];
  #pragma unroll
  for (int j = 0; j < 5; ++j) t[j] = p[j];   // each slot already sorted ascending
  #pragma unroll
  for (int off = 1; off < 64; off <<= 1) {
    float o[5];
    #pragma unroll
    for (int j = 0; j < 5; ++j) o[j] = __shfl_xor(t[j], off, 64);
    #pragma unroll
    for (int j = 0; j < 5; ++j) insert5(t, o[j]);
  }
  if (lane == 0) {
    float sc = 0.f;
    #pragma unroll
    for (int j = 0; j < 5; ++j) sc += sqrtf(fmaxf(t[j], 0.f));
    sc *= 0.2f;  // mean of 5
    w[r] = (sc > PTH) ? expf(-sc / TAU) : 0.f;
  }
}

__global__ void apply_kernel(const float* __restrict__ xr, const float* __restrict__ xi,
                             const float* __restrict__ w, float* __restrict__ out, int N) {
  const size_t i = (size_t)blockIdx.x * blockDim.x + threadIdx.x;
  const size_t tot = (size_t)N * (DD / 4);
  if (i >= tot) return;
  const int row = (int)(i >> 8);  // DD/4 = 256 float4 per row
  const float wt = w[row];
  float4 a = reinterpret_cast<const float4*>(xr)[i];
  a.x *= wt; a.y *= wt; a.z *= wt; a.w *= wt;
  reinterpret_cast<float4*>(out)[i] = a;
  float4 b = reinterpret_cast<const float4*>(xi)[i];
  b.x *= wt; b.y *= wt; b.z *= wt; b.w *= wt;
  reinterpret_cast<float4*>(out)[tot + i] = b;
}

extern "C" void kernel_launch(void* const* d_in, const int* in_sizes, int n_in,
                              void* d_out, int out_size, void* d_ws, size_t ws_size,
                              hipStream_t stream) {
  const float* xr = (const float*)d_in[0];
  const float* xi = (const float*)d_in[1];
  float* out = (float*)d_out;
  const int N = in_sizes[0] / DD;  // 8192
  const int NBv = N / BM;          // 64
  const int NSB = NBv / 8;         // 8

  unsigned short* xbf = (unsigned short*)d_ws;                       // N*DD bf16
  float* sq      = (float*)((char*)d_ws + (size_t)N * DD * 2);       // N f32
  float* partial = sq + N;                                           // N*NBv*5 f32 (10.5 MB)
  float* w       = partial + (size_t)N * NBv * 5;                    // N f32

  prep_kernel<<<N / 4, 256, 0, stream>>>(xr, xbf, sq);
  const int nsp = NSB * (NSB + 1) / 2;      // 36 super-pairs
  gemm_topk_kernel<<<nsp * 64, 256, 0, stream>>>(xbf, sq, partial, N);  // 2304 blocks
  weight_kernel<<<N / 4, 256, 0, stream>>>(partial, w, N);
  apply_kernel<<<N, 256, 0, stream>>>(xr, xi, w, out, N);
}